// Round 5
// baseline (455.171 us; speedup 1.0000x reference)
//
#include <hip/hip_runtime.h>

#define ALPHA 0.2f
#define NN 8192
#define FIN 128
#define FOUT 64

typedef short bf16x8 __attribute__((ext_vector_type(8)));
typedef float f32x4 __attribute__((ext_vector_type(4)));

__device__ __forceinline__ unsigned short f2b(float x) {
    unsigned u = __builtin_bit_cast(unsigned, x);
    unsigned r = (u + 0x7fffu + ((u >> 16) & 1u)) >> 16;  // RNE
    return (unsigned short)r;
}

// K0: compress adj -> bitmasks. Wave sweeps one row linearly (coalesced 1KB/instr).
// Layout: adjb[row][grp][c] (c=0..3), bit l of word c = adj[row][grp*256 + 4*l + c].
__global__ __launch_bounds__(256) void gat_k0(const int* __restrict__ adj,
                                              unsigned long long* __restrict__ adjb) {
    int t = threadIdx.x, w = t >> 6, l = t & 63;
    int row = blockIdx.x * 4 + w;
    const int4* a4 = (const int4*)(adj + (size_t)row * NN);
    unsigned long long* ob = adjb + (size_t)row * 32 * 4;
#pragma unroll 4
    for (int it = 0; it < 32; ++it) {
        int4 av = a4[it * 64 + l];
        unsigned long long b0 = __ballot(av.x != 0);
        unsigned long long b1 = __ballot(av.y != 0);
        unsigned long long b2 = __ballot(av.z != 0);
        unsigned long long b3 = __ballot(av.w != 0);
        if (l == 0) {
            ulonglong4 v;
            v.x = b0; v.y = b1; v.z = b2; v.w = b3;
            *(ulonglong4*)(ob + it * 4) = v;
        }
    }
}

// K1: Wh = h @ W  [8192x64] f32, src = Wh @ a[:64], dst = Wh @ a[64:]
__global__ __launch_bounds__(256) void gat_k1(const float* __restrict__ h,
                                              const float* __restrict__ W,
                                              const float* __restrict__ a,
                                              float* __restrict__ Wh,
                                              float* __restrict__ src,
                                              float* __restrict__ dst) {
    __shared__ float wlds[FIN * FOUT];  // 32 KB
    int t = threadIdx.x;
    const float4* W4 = (const float4*)W;
    float4* wlds4 = (float4*)wlds;
#pragma unroll
    for (int q = 0; q < 8; ++q) wlds4[q * 256 + t] = W4[q * 256 + t];
    __syncthreads();
    int wave = t >> 6, lane = t & 63;
    int row = blockIdx.x * 4 + wave;
    const float4* h4 = (const float4*)(h + (size_t)row * FIN);
    float acc = 0.f;
#pragma unroll
    for (int k4 = 0; k4 < 32; ++k4) {
        float4 hv = h4[k4];
        acc = fmaf(hv.x, wlds[(k4 * 4 + 0) * 64 + lane], acc);
        acc = fmaf(hv.y, wlds[(k4 * 4 + 1) * 64 + lane], acc);
        acc = fmaf(hv.z, wlds[(k4 * 4 + 2) * 64 + lane], acc);
        acc = fmaf(hv.w, wlds[(k4 * 4 + 3) * 64 + lane], acc);
    }
    Wh[(size_t)row * 64 + lane] = acc;
    float sa = acc * a[lane];
    float da = acc * a[64 + lane];
#pragma unroll
    for (int off = 32; off; off >>= 1) {
        sa += __shfl_xor(sa, off);
        da += __shfl_xor(da, off);
    }
    if (lane == 0) { src[row] = sa; dst[row] = da; }
}

// K1b: WhbT[f][j] = bf16(Wh[j][f])  -- 64 x 8192 bf16 (1 MB), for MFMA B-fragments.
__global__ __launch_bounds__(256) void gat_k1b(const float* __restrict__ Wh,
                                               unsigned short* __restrict__ whbt) {
    __shared__ unsigned short t16[64 * 68];
    int t = threadIdx.x;
    int rb = blockIdx.x * 64;
    const float4* s4 = (const float4*)(Wh + (size_t)rb * 64);
#pragma unroll
    for (int q = 0; q < 4; ++q) {
        float4 v = s4[t * 4 + q];
        int flat = t * 16 + q * 4;
        int r = flat >> 6, f = flat & 63;
        unsigned short* p = &t16[r * 68 + f];
        p[0] = f2b(v.x); p[1] = f2b(v.y); p[2] = f2b(v.z); p[3] = f2b(v.w);
    }
    __syncthreads();
    int f = t >> 2, qr = t & 3;
    unsigned v[8];
#pragma unroll
    for (int k = 0; k < 8; ++k) {
        unsigned lo = t16[(qr * 16 + 2 * k + 0) * 68 + f];
        unsigned hi = t16[(qr * 16 + 2 * k + 1) * 68 + f];
        v[k] = lo | (hi << 16);
    }
    uint4* o = (uint4*)(whbt + (size_t)f * NN + rb + qr * 16);
    o[0] = make_uint4(v[0], v[1], v[2], v[3]);
    o[1] = make_uint4(v[4], v[5], v[6], v[7]);
}

// K2: fused mask + exp + PV via MFMA. Block = 256 (4 waves); wave owns 16 rows x 64 f.
// adj comes from L2-resident bitmasks (no HBM gather). Row-sum via 5th MFMA (ones-B).
__global__ __launch_bounds__(256) void gat_k2(const unsigned long long* __restrict__ adjb,
                                              const unsigned short* __restrict__ whbt,
                                              const float* __restrict__ src,
                                              const float* __restrict__ dst,
                                              float* __restrict__ pl,
                                              float* __restrict__ pacc,
                                              int ns, int js) {
    const int l = threadIdx.x & 63;
    const int w = threadIdx.x >> 6;
    const int r = l & 15;          // A row / C col index
    const int g = l >> 4;          // k-group
    const int s = blockIdx.x;
    const int rg = blockIdx.y;
    const int task = rg * ns + s;
    const int row = rg * 64 + w * 16 + r;
    const int j0 = s * js;

    const float srcv = src[row];
    const float4* dst4 = (const float4*)dst;
    const unsigned long long* brow = adjb + (size_t)row * 32 * 4;

    f32x4 acc0 = {0.f, 0.f, 0.f, 0.f}, acc1 = acc0, acc2 = acc0, acc3 = acc0, accl = acc0;
    bf16x8 bones;
#pragma unroll
    for (int e = 0; e < 8; ++e) bones[e] = (short)0x3F80;  // bf16 1.0

    const int g0 = j0 >> 8, g1 = (j0 + js) >> 8;
    ulonglong2 mA = *(const ulonglong2*)(brow + g0 * 4);
    ulonglong2 mB = *(const ulonglong2*)(brow + g0 * 4 + 2);

    for (int grp = g0; grp < g1; ++grp) {
        int ng = (grp + 1 < g1) ? grp + 1 : g0;  // wrap (discarded)
        ulonglong2 nA = *(const ulonglong2*)(brow + ng * 4);
        ulonglong2 nB = *(const ulonglong2*)(brow + ng * 4 + 2);
        unsigned long long m0 = mA.x, m1 = mA.y, m2 = mB.x, m3 = mB.y;
        const int jgrp = grp << 8;
#pragma unroll 2
        for (int hh = 0; hh < 8; ++hh) {
            const int jh = jgrp + hh * 32;
            const int hb = hh * 8 + 2 * g;  // bit base within mask words
            float4 d0 = dst4[(jh >> 2) + 2 * g];
            float4 d1 = dst4[(jh >> 2) + 2 * g + 1];
            float xs[8] = {d0.x, d0.y, d0.z, d0.w, d1.x, d1.y, d1.z, d1.w};
            float p[8];
#pragma unroll
            for (int e = 0; e < 8; ++e) {
                float x = srcv + xs[e];
                float lr = fmaxf(x, 0.f) + ALPHA * fminf(x, 0.f);
                float pe = __expf(lr);
                unsigned long long mm = (e & 3) == 0 ? m0 : (e & 3) == 1 ? m1
                                      : (e & 3) == 2 ? m2 : m3;
                unsigned bit = (unsigned)(mm >> (hb + (e >> 2))) & 1u;
                p[e] = bit ? pe : 0.f;
            }
            unsigned pw0, pw1, pw2, pw3;
            asm("v_cvt_pk_bf16_f32 %0, %1, %2" : "=v"(pw0) : "v"(p[0]), "v"(p[1]));
            asm("v_cvt_pk_bf16_f32 %0, %1, %2" : "=v"(pw1) : "v"(p[2]), "v"(p[3]));
            asm("v_cvt_pk_bf16_f32 %0, %1, %2" : "=v"(pw2) : "v"(p[4]), "v"(p[5]));
            asm("v_cvt_pk_bf16_f32 %0, %1, %2" : "=v"(pw3) : "v"(p[6]), "v"(p[7]));
            uint4 pwv = make_uint4(pw0, pw1, pw2, pw3);
            bf16x8 af = __builtin_bit_cast(bf16x8, pwv);

            const unsigned short* bbase = whbt + (size_t)r * NN + jh + 8 * g;
            bf16x8 b0 = *(const bf16x8*)(bbase + 0 * 16 * NN);
            bf16x8 b1 = *(const bf16x8*)(bbase + 1 * 16 * NN);
            bf16x8 b2 = *(const bf16x8*)(bbase + 2 * 16 * NN);
            bf16x8 b3 = *(const bf16x8*)(bbase + 3 * 16 * NN);
            acc0 = __builtin_amdgcn_mfma_f32_16x16x32_bf16(af, b0, acc0, 0, 0, 0);
            acc1 = __builtin_amdgcn_mfma_f32_16x16x32_bf16(af, b1, acc1, 0, 0, 0);
            acc2 = __builtin_amdgcn_mfma_f32_16x16x32_bf16(af, b2, acc2, 0, 0, 0);
            acc3 = __builtin_amdgcn_mfma_f32_16x16x32_bf16(af, b3, acc3, 0, 0, 0);
            accl = __builtin_amdgcn_mfma_f32_16x16x32_bf16(af, bones, accl, 0, 0, 0);
        }
        mA = nA; mB = nB;
    }

    // accl: row m = g*4+reg, all 16 cols identical -> store from col lane r==0
    if (r == 0) {
        float* plo = pl + (size_t)task * 64 + w * 16 + g * 4;
        plo[0] = accl[0]; plo[1] = accl[1]; plo[2] = accl[2]; plo[3] = accl[3];
    }

    // C layout (verified): col = lane&15, row_m = (lane>>4)*4 + reg
    float* po = pacc + (size_t)task * 4096 + (size_t)(w * 16) * 64;
#pragma unroll
    for (int reg = 0; reg < 4; ++reg) {
        int m = g * 4 + reg;
        po[m * 64 + 0 * 16 + r] = acc0[reg];
        po[m * 64 + 1 * 16 + r] = acc1[reg];
        po[m * 64 + 2 * 16 + r] = acc2[reg];
        po[m * 64 + 3 * 16 + r] = acc3[reg];
    }
}

// K3: combine split partials + ELU. block=256 (4 waves), wave=row, lane=f.
__global__ __launch_bounds__(256) void gat_k3(const float* __restrict__ pl,
                                              const float* __restrict__ pacc,
                                              float* __restrict__ out, int ns) {
    int t = threadIdx.x;
    int wave = t >> 6, lane = t & 63;
    int row = blockIdx.x * 4 + wave;
    int rg = row >> 6, rr = row & 63;
    float L = 0.f, o = 0.f;
    for (int s2 = 0; s2 < ns; ++s2) {
        L += pl[(size_t)(rg * ns + s2) * 64 + rr];
        o += pacc[(size_t)(rg * ns + s2) * 4096 + rr * 64 + lane];
    }
    float hp = o / L;
    out[(size_t)row * 64 + lane] = hp > 0.f ? hp : __expf(hp) - 1.f;
}

extern "C" void kernel_launch(void* const* d_in, const int* in_sizes, int n_in,
                              void* d_out, int out_size, void* d_ws, size_t ws_size,
                              hipStream_t stream) {
    const float* h = (const float*)d_in[0];
    const int* adj = (const int*)d_in[1];
    const float* W = (const float*)d_in[2];
    const float* a = (const float*)d_in[3];
    float* out = (float*)d_out;
    float* ws = (float*)d_ws;

    size_t avail = ws_size / sizeof(float);
    int ns = 4;
    // floats: Wh 524288 + src/dst 16384 + whbt 262144 + adjb 2097152 + ns*(pl 8192 + pacc 524288)
    while (ns > 1 && (size_t)2899968 + (size_t)ns * 532480 > avail) ns >>= 1;
    int js = NN / ns;

    float* Wh = ws;                                   // 524288
    float* src = Wh + (size_t)NN * FOUT;              // 8192
    float* dst = src + NN;                            // 8192
    float* pl = dst + NN;                             // 128*ns*64
    float* pacc = pl + (size_t)128 * ns * 64;         // 128*ns*4096
    unsigned short* whbt = (unsigned short*)(pacc + (size_t)128 * ns * 4096);  // 262144 f32
    unsigned long long* adjb = (unsigned long long*)((float*)whbt + 262144);   // 8 MB

    gat_k0<<<dim3(NN / 4), dim3(256), 0, stream>>>(adj, adjb);
    gat_k1<<<dim3(NN / 4), dim3(256), 0, stream>>>(h, W, a, Wh, src, dst);
    gat_k1b<<<dim3(NN / 64), dim3(256), 0, stream>>>(Wh, whbt);
    gat_k2<<<dim3(ns, 128), dim3(256), 0, stream>>>(adjb, whbt, src, dst, pl, pacc, ns, js);
    gat_k3<<<dim3(NN / 4), dim3(256), 0, stream>>>(pl, pacc, out, ns);
}

// Round 6
// 445.913 us; speedup vs baseline: 1.0208x; 1.0208x over previous
//
#include <hip/hip_runtime.h>

#define ALPHA 0.2f
#define NN 8192
#define FIN 128
#define FOUT 64

typedef short bf16x8 __attribute__((ext_vector_type(8)));
typedef float f32x4 __attribute__((ext_vector_type(4)));

// K0: compress adj -> bitmasks. Wave sweeps one row linearly (coalesced 1KB/instr).
// Layout: adjb[row][grp][c] (c=0..3), bit l of word c = adj[row][grp*256 + 4*l + c].
__global__ __launch_bounds__(256) void gat_k0(const int* __restrict__ adj,
                                              unsigned long long* __restrict__ adjb) {
    int t = threadIdx.x, w = t >> 6, l = t & 63;
    int row = blockIdx.x * 4 + w;
    const int4* a4 = (const int4*)(adj + (size_t)row * NN);
    unsigned long long* ob = adjb + (size_t)row * 32 * 4;
#pragma unroll 4
    for (int it = 0; it < 32; ++it) {
        int4 av = a4[it * 64 + l];
        unsigned long long b0 = __ballot(av.x != 0);
        unsigned long long b1 = __ballot(av.y != 0);
        unsigned long long b2 = __ballot(av.z != 0);
        unsigned long long b3 = __ballot(av.w != 0);
        if (l == 0) {
            ulonglong4 v;
            v.x = b0; v.y = b1; v.z = b2; v.w = b3;
            *(ulonglong4*)(ob + it * 4) = v;
        }
    }
}

// K1: Wh = h @ W  [8192x64] f32, src = Wh @ a[:64], dst = Wh @ a[64:]
__global__ __launch_bounds__(256) void gat_k1(const float* __restrict__ h,
                                              const float* __restrict__ W,
                                              const float* __restrict__ a,
                                              float* __restrict__ Wh,
                                              float* __restrict__ src,
                                              float* __restrict__ dst) {
    __shared__ float wlds[FIN * FOUT];  // 32 KB
    int t = threadIdx.x;
    const float4* W4 = (const float4*)W;
    float4* wlds4 = (float4*)wlds;
#pragma unroll
    for (int q = 0; q < 8; ++q) wlds4[q * 256 + t] = W4[q * 256 + t];
    __syncthreads();
    int wave = t >> 6, lane = t & 63;
    int row = blockIdx.x * 4 + wave;
    const float4* h4 = (const float4*)(h + (size_t)row * FIN);
    float acc = 0.f;
#pragma unroll
    for (int k4 = 0; k4 < 32; ++k4) {
        float4 hv = h4[k4];
        acc = fmaf(hv.x, wlds[(k4 * 4 + 0) * 64 + lane], acc);
        acc = fmaf(hv.y, wlds[(k4 * 4 + 1) * 64 + lane], acc);
        acc = fmaf(hv.z, wlds[(k4 * 4 + 2) * 64 + lane], acc);
        acc = fmaf(hv.w, wlds[(k4 * 4 + 3) * 64 + lane], acc);
    }
    Wh[(size_t)row * 64 + lane] = acc;
    float sa = acc * a[lane];
    float da = acc * a[64 + lane];
#pragma unroll
    for (int off = 32; off; off >>= 1) {
        sa += __shfl_xor(sa, off);
        da += __shfl_xor(da, off);
    }
    if (lane == 0) { src[row] = sa; dst[row] = da; }
}

// K1b: build MFMA-ready B fragments.
// whbt2[tile t][frag q][lane l] (uint4 = 8 bf16): elem e = bf16(Wh[32t + 8*(l>>4) + e][16q + (l&15)]).
// One block per tile (32 j-rows); wave q emits frag q; stores perfectly coalesced.
__global__ __launch_bounds__(256) void gat_k1b(const float* __restrict__ Wh,
                                               uint4* __restrict__ whbt2) {
    __shared__ float wt[32 * 64];  // 8 KB
    int tid = threadIdx.x;
    int t = blockIdx.x;
    const float4* s4 = (const float4*)(Wh + (size_t)t * 2048);
    float4* l4 = (float4*)wt;
    l4[tid] = s4[tid];
    l4[tid + 256] = s4[tid + 256];
    __syncthreads();
    int q = tid >> 6, l = tid & 63, r = l & 15, g = l >> 4;
    unsigned pk[4];
#pragma unroll
    for (int k = 0; k < 4; ++k) {
        float lo = wt[(8 * g + 2 * k + 0) * 64 + 16 * q + r];
        float hi = wt[(8 * g + 2 * k + 1) * 64 + 16 * q + r];
        asm("v_cvt_pk_bf16_f32 %0, %1, %2" : "=v"(pk[k]) : "v"(lo), "v"(hi));
    }
    whbt2[(size_t)t * 256 + tid] = make_uint4(pk[0], pk[1], pk[2], pk[3]);
}

// K2: fused mask + exp + PV via MFMA, one-step-ahead register pipeline.
// Block = 256 (4 waves, 4 blocks/CU); wave owns 16 rows x 64 f; lane=(g,r).
// All steady-state loads (b-frags, masks) prefetched one step ahead; dst is L1-hot.
__global__ __launch_bounds__(256, 4) void gat_k2(const unsigned long long* __restrict__ adjb,
                                                 const uint4* __restrict__ whbt2,
                                                 const float* __restrict__ src,
                                                 const float* __restrict__ dst,
                                                 float* __restrict__ pl,
                                                 float* __restrict__ pacc,
                                                 int ns, int js) {
    const int l = threadIdx.x & 63;
    const int w = threadIdx.x >> 6;
    const int r = l & 15;          // A row / C col index
    const int g = l >> 4;          // k-group
    const int s = blockIdx.x;
    const int rg = blockIdx.y;
    const int task = rg * ns + s;
    const int row = rg * 64 + w * 16 + r;
    const int j0 = s * js;
    const int steps = js >> 5;

    const float srcv = src[row];
    const float4* dst4 = (const float4*)dst;
    const ulonglong2* brow2 = (const ulonglong2*)(adjb + (size_t)row * 128);
    const uint4* bt = whbt2 + l;

    f32x4 acc0 = {0.f, 0.f, 0.f, 0.f}, acc1 = acc0, acc2 = acc0, acc3 = acc0, accl = acc0;
    bf16x8 bones;
#pragma unroll
    for (int e = 0; e < 8; ++e) bones[e] = (short)0x3F80;  // bf16 1.0

    // prologue: loads for step 0
    int jh = j0;
    uint4 b0 = bt[(jh >> 5) * 256 + 0 * 64];
    uint4 b1 = bt[(jh >> 5) * 256 + 1 * 64];
    uint4 b2 = bt[(jh >> 5) * 256 + 2 * 64];
    uint4 b3 = bt[(jh >> 5) * 256 + 3 * 64];
    ulonglong2 mA = brow2[(jh >> 8) * 2 + 0];
    ulonglong2 mB = brow2[(jh >> 8) * 2 + 1];

    for (int t = 0; t < steps; ++t, jh += 32) {
        // ---- issue next-step loads first (independent of this step's compute)
        const int jn = (t + 1 < steps) ? jh + 32 : j0;  // wrap: values discarded
        uint4 nb0 = bt[(jn >> 5) * 256 + 0 * 64];
        uint4 nb1 = bt[(jn >> 5) * 256 + 1 * 64];
        uint4 nb2 = bt[(jn >> 5) * 256 + 2 * 64];
        uint4 nb3 = bt[(jn >> 5) * 256 + 3 * 64];
        ulonglong2 nmA = brow2[(jn >> 8) * 2 + 0];
        ulonglong2 nmB = brow2[(jn >> 8) * 2 + 1];

        // ---- this step's compute (dst is L1-hot; masks/b in registers)
        float4 d0 = dst4[(jh >> 2) + 2 * g];
        float4 d1 = dst4[(jh >> 2) + 2 * g + 1];
        const int hb = ((jh >> 5) & 7) * 8 + 2 * g;
        const unsigned long long m0 = mA.x, m1 = mA.y, m2 = mB.x, m3 = mB.y;

        float p[8];
        {
            float xs[8] = {d0.x, d0.y, d0.z, d0.w, d1.x, d1.y, d1.z, d1.w};
#pragma unroll
            for (int e = 0; e < 8; ++e) {
                float x = srcv + xs[e];
                float lr = fmaxf(x, 0.f) + ALPHA * fminf(x, 0.f);
                float pe = __expf(lr);
                unsigned long long mm = (e & 3) == 0 ? m0 : (e & 3) == 1 ? m1
                                      : (e & 3) == 2 ? m2 : m3;
                unsigned bit = (unsigned)(mm >> (hb + (e >> 2))) & 1u;
                p[e] = bit ? pe : 0.f;
            }
        }
        unsigned pw0, pw1, pw2, pw3;
        asm("v_cvt_pk_bf16_f32 %0, %1, %2" : "=v"(pw0) : "v"(p[0]), "v"(p[1]));
        asm("v_cvt_pk_bf16_f32 %0, %1, %2" : "=v"(pw1) : "v"(p[2]), "v"(p[3]));
        asm("v_cvt_pk_bf16_f32 %0, %1, %2" : "=v"(pw2) : "v"(p[4]), "v"(p[5]));
        asm("v_cvt_pk_bf16_f32 %0, %1, %2" : "=v"(pw3) : "v"(p[6]), "v"(p[7]));
        bf16x8 af = __builtin_bit_cast(bf16x8, make_uint4(pw0, pw1, pw2, pw3));

        acc0 = __builtin_amdgcn_mfma_f32_16x16x32_bf16(af, __builtin_bit_cast(bf16x8, b0), acc0, 0, 0, 0);
        acc1 = __builtin_amdgcn_mfma_f32_16x16x32_bf16(af, __builtin_bit_cast(bf16x8, b1), acc1, 0, 0, 0);
        acc2 = __builtin_amdgcn_mfma_f32_16x16x32_bf16(af, __builtin_bit_cast(bf16x8, b2), acc2, 0, 0, 0);
        acc3 = __builtin_amdgcn_mfma_f32_16x16x32_bf16(af, __builtin_bit_cast(bf16x8, b3), acc3, 0, 0, 0);
        accl = __builtin_amdgcn_mfma_f32_16x16x32_bf16(af, bones, accl, 0, 0, 0);

        // ---- rotate pipeline
        b0 = nb0; b1 = nb1; b2 = nb2; b3 = nb3;
        mA = nmA; mB = nmB;
    }

    // accl: row m = g*4+reg, all 16 cols identical -> store from col lane r==0
    if (r == 0) {
        float* plo = pl + (size_t)task * 64 + w * 16 + g * 4;
        plo[0] = accl[0]; plo[1] = accl[1]; plo[2] = accl[2]; plo[3] = accl[3];
    }

    // C layout (verified): col = lane&15, row_m = (lane>>4)*4 + reg
    float* po = pacc + (size_t)task * 4096 + (size_t)(w * 16) * 64;
#pragma unroll
    for (int reg = 0; reg < 4; ++reg) {
        int m = g * 4 + reg;
        po[m * 64 + 0 * 16 + r] = acc0[reg];
        po[m * 64 + 1 * 16 + r] = acc1[reg];
        po[m * 64 + 2 * 16 + r] = acc2[reg];
        po[m * 64 + 3 * 16 + r] = acc3[reg];
    }
}

// K3: combine split partials + ELU. block=256 (4 waves), wave=row, lane=f.
__global__ __launch_bounds__(256) void gat_k3(const float* __restrict__ pl,
                                              const float* __restrict__ pacc,
                                              float* __restrict__ out, int ns) {
    int t = threadIdx.x;
    int wave = t >> 6, lane = t & 63;
    int row = blockIdx.x * 4 + wave;
    int rg = row >> 6, rr = row & 63;
    float L = 0.f, o = 0.f;
    for (int s2 = 0; s2 < ns; ++s2) {
        L += pl[(size_t)(rg * ns + s2) * 64 + rr];
        o += pacc[(size_t)(rg * ns + s2) * 4096 + rr * 64 + lane];
    }
    float hp = o / L;
    out[(size_t)row * 64 + lane] = hp > 0.f ? hp : __expf(hp) - 1.f;
}

extern "C" void kernel_launch(void* const* d_in, const int* in_sizes, int n_in,
                              void* d_out, int out_size, void* d_ws, size_t ws_size,
                              hipStream_t stream) {
    const float* h = (const float*)d_in[0];
    const int* adj = (const int*)d_in[1];
    const float* W = (const float*)d_in[2];
    const float* a = (const float*)d_in[3];
    float* out = (float*)d_out;
    float* ws = (float*)d_ws;

    size_t avail = ws_size / sizeof(float);
    int ns = 8;
    // floats: Wh 524288 + src/dst 16384 + whbt2 262144 + adjb 2097152 + ns*(pl 8192 + pacc 524288)
    while (ns > 1 && (size_t)2899968 + (size_t)ns * 532480 > avail) ns >>= 1;
    int js = NN / ns;

    float* Wh = ws;                                   // 524288
    float* src = Wh + (size_t)NN * FOUT;              // 8192
    float* dst = src + NN;                            // 8192
    float* pl = dst + NN;                             // 128*ns*64
    float* pacc = pl + (size_t)128 * ns * 64;         // 128*ns*4096
    uint4* whbt2 = (uint4*)(pacc + (size_t)128 * ns * 4096);                 // 1 MB
    unsigned long long* adjb = (unsigned long long*)((float*)whbt2 + 262144); // 8 MB

    gat_k0<<<dim3(NN / 4), dim3(256), 0, stream>>>(adj, adjb);
    gat_k1<<<dim3(NN / 4), dim3(256), 0, stream>>>(h, W, a, Wh, src, dst);
    gat_k1b<<<dim3(NN / 32), dim3(256), 0, stream>>>(Wh, whbt2);
    gat_k2<<<dim3(ns, 128), dim3(256), 0, stream>>>(adjb, whbt2, src, dst, pl, pacc, ns, js);
    gat_k3<<<dim3(NN / 4), dim3(256), 0, stream>>>(pl, pacc, out, ns);
}

// Round 7
// 420.013 us; speedup vs baseline: 1.0837x; 1.0617x over previous
//
#include <hip/hip_runtime.h>

#define ALPHA 0.2f
#define NN 8192
#define FIN 128
#define FOUT 64
#define NS 16
#define JS 512

typedef short bf16x8 __attribute__((ext_vector_type(8)));
typedef float f32x4 __attribute__((ext_vector_type(4)));

__device__ __forceinline__ unsigned short f2b(float x) {
    unsigned u = __builtin_bit_cast(unsigned, x);
    unsigned r = (u + 0x7fffu + ((u >> 16) & 1u)) >> 16;  // RNE
    return (unsigned short)r;
}

// K0: compress adj -> bitmasks. Wave sweeps one row linearly (coalesced 1KB/instr).
// Layout: adjb[row][grp][c] (c=0..3), bit l of word c = adj[row][grp*256 + 4*l + c].
__global__ __launch_bounds__(256) void gat_k0(const int* __restrict__ adj,
                                              unsigned long long* __restrict__ adjb) {
    int t = threadIdx.x, w = t >> 6, l = t & 63;
    int row = blockIdx.x * 4 + w;
    const int4* a4 = (const int4*)(adj + (size_t)row * NN);
    unsigned long long* ob = adjb + (size_t)row * 32 * 4;
#pragma unroll 4
    for (int it = 0; it < 32; ++it) {
        int4 av = a4[it * 64 + l];
        unsigned long long b0 = __ballot(av.x != 0);
        unsigned long long b1 = __ballot(av.y != 0);
        unsigned long long b2 = __ballot(av.z != 0);
        unsigned long long b3 = __ballot(av.w != 0);
        if (l == 0) {
            ulonglong4 v;
            v.x = b0; v.y = b1; v.z = b2; v.w = b3;
            *(ulonglong4*)(ob + it * 4) = v;
        }
    }
}

// K1: Wh = h @ W  [8192x64] f32, src = Wh @ a[:64], dst = Wh @ a[64:]
__global__ __launch_bounds__(256) void gat_k1(const float* __restrict__ h,
                                              const float* __restrict__ W,
                                              const float* __restrict__ a,
                                              float* __restrict__ Wh,
                                              float* __restrict__ src,
                                              float* __restrict__ dst) {
    __shared__ float wlds[FIN * FOUT];  // 32 KB
    int t = threadIdx.x;
    const float4* W4 = (const float4*)W;
    float4* wlds4 = (float4*)wlds;
#pragma unroll
    for (int q = 0; q < 8; ++q) wlds4[q * 256 + t] = W4[q * 256 + t];
    __syncthreads();
    int wave = t >> 6, lane = t & 63;
    int row = blockIdx.x * 4 + wave;
    const float4* h4 = (const float4*)(h + (size_t)row * FIN);
    float acc = 0.f;
#pragma unroll
    for (int k4 = 0; k4 < 32; ++k4) {
        float4 hv = h4[k4];
        acc = fmaf(hv.x, wlds[(k4 * 4 + 0) * 64 + lane], acc);
        acc = fmaf(hv.y, wlds[(k4 * 4 + 1) * 64 + lane], acc);
        acc = fmaf(hv.z, wlds[(k4 * 4 + 2) * 64 + lane], acc);
        acc = fmaf(hv.w, wlds[(k4 * 4 + 3) * 64 + lane], acc);
    }
    Wh[(size_t)row * 64 + lane] = acc;
    float sa = acc * a[lane];
    float da = acc * a[64 + lane];
#pragma unroll
    for (int off = 32; off; off >>= 1) {
        sa += __shfl_xor(sa, off);
        da += __shfl_xor(da, off);
    }
    if (lane == 0) { src[row] = sa; dst[row] = da; }
}

// K1b: build MFMA-ready B fragments.
// whbt2[tile t][frag q][lane l] (uint4 = 8 bf16): elem e = bf16(Wh[32t + 8*(l>>4) + e][16q + (l&15)]).
__global__ __launch_bounds__(256) void gat_k1b(const float* __restrict__ Wh,
                                               uint4* __restrict__ whbt2) {
    __shared__ float wt[32 * 64];  // 8 KB
    int tid = threadIdx.x;
    int t = blockIdx.x;
    const float4* s4 = (const float4*)(Wh + (size_t)t * 2048);
    float4* l4 = (float4*)wt;
    l4[tid] = s4[tid];
    l4[tid + 256] = s4[tid + 256];
    __syncthreads();
    int q = tid >> 6, l = tid & 63, r = l & 15, g = l >> 4;
    unsigned pk[4];
#pragma unroll
    for (int k = 0; k < 4; ++k) {
        float lo = wt[(8 * g + 2 * k + 0) * 64 + 16 * q + r];
        float hi = wt[(8 * g + 2 * k + 1) * 64 + 16 * q + r];
        asm("v_cvt_pk_bf16_f32 %0, %1, %2" : "=v"(pk[k]) : "v"(lo), "v"(hi));
    }
    whbt2[(size_t)t * 256 + tid] = make_uint4(pk[0], pk[1], pk[2], pk[3]);
}

// K2: fused mask + exp + PV via MFMA. Block = 256 (4 waves); wave owns 16 rows x 64 f.
// ALL steady-state data staged in LDS once per block (70 KB): B tiles 64K, masks 4K, dst 2K.
// Zero global loads in the 16-step main loop -> no vmcnt on the critical path.
__global__ __launch_bounds__(256, 2) void gat_k2(const unsigned long long* __restrict__ adjb,
                                                 const uint4* __restrict__ whbt2,
                                                 const float* __restrict__ src,
                                                 const float* __restrict__ dst,
                                                 float* __restrict__ pl,
                                                 float* __restrict__ pacc) {
    __shared__ uint4 lds_b[16 * 256];     // 64 KB: 16 j-tiles x 256 frags
    __shared__ ulonglong2 lds_m[4 * 64];  // 4 KB: [chunk c][row rho] = adjb words {4*(j0>>8).. } pairwise
    __shared__ float lds_d[JS];           // 2 KB
    const int tid = threadIdx.x;
    const int l = tid & 63, w = tid >> 6;
    const int r = l & 15, g = l >> 4;
    const int s = blockIdx.x, rg = blockIdx.y;
    const int task = rg * NS + s;
    const int rowbase = rg * 64;
    const int rho = w * 16 + r;
    const int row = rowbase + rho;
    const int j0 = s * JS;

    // ---- stage (fire-and-forget; one barrier)
    const uint4* bsrc = whbt2 + (size_t)(j0 >> 5) * 256;
#pragma unroll
    for (int k = 0; k < 16; ++k) lds_b[k * 256 + tid] = bsrc[k * 256 + tid];
    {   // thread T: mask row T&63, chunk T>>6 (16 B each)
        const ulonglong2* msrc =
            (const ulonglong2*)(adjb + (size_t)(rowbase + (tid & 63)) * 128 + (size_t)(j0 >> 8) * 4) + (tid >> 6);
        lds_m[tid] = *msrc;
    }
    if (tid < JS / 4) ((float4*)lds_d)[tid] = ((const float4*)(dst + j0))[tid];
    __syncthreads();

    const float srcv = src[row];
    f32x4 acc0 = {0.f, 0.f, 0.f, 0.f}, acc1 = acc0, acc2 = acc0, acc3 = acc0, accl = acc0;
    bf16x8 bones;
#pragma unroll
    for (int e = 0; e < 8; ++e) bones[e] = (short)0x3F80;  // bf16 1.0

    // both mask groups preloaded (broadcast reads)
    ulonglong2 g0a = lds_m[0 * 64 + rho], g0b = lds_m[1 * 64 + rho];
    ulonglong2 g1a = lds_m[2 * 64 + rho], g1b = lds_m[3 * 64 + rho];

    // prologue: step-0 operands
    uint4 cb0 = lds_b[0 * 64 + l], cb1 = lds_b[1 * 64 + l], cb2 = lds_b[2 * 64 + l], cb3 = lds_b[3 * 64 + l];
    float4 cd0 = *(const float4*)(lds_d + g * 8);
    float4 cd1 = *(const float4*)(lds_d + g * 8 + 4);

#pragma unroll
    for (int t = 0; t < 16; ++t) {
        // ---- prefetch next step's operands from LDS (independent)
        const int tn = (t + 1) & 15;
        uint4 nb0 = lds_b[tn * 256 + 0 * 64 + l];
        uint4 nb1 = lds_b[tn * 256 + 1 * 64 + l];
        uint4 nb2 = lds_b[tn * 256 + 2 * 64 + l];
        uint4 nb3 = lds_b[tn * 256 + 3 * 64 + l];
        float4 nd0 = *(const float4*)(lds_d + tn * 32 + g * 8);
        float4 nd1 = *(const float4*)(lds_d + tn * 32 + g * 8 + 4);

        // ---- current step compute (registers only)
        const unsigned long long m0 = (t < 8) ? g0a.x : g1a.x;
        const unsigned long long m1 = (t < 8) ? g0a.y : g1a.y;
        const unsigned long long m2 = (t < 8) ? g0b.x : g1b.x;
        const unsigned long long m3 = (t < 8) ? g0b.y : g1b.y;
        const int hb = (t & 7) * 8 + 2 * g;

        float p[8];
        {
            float xs[8] = {cd0.x, cd0.y, cd0.z, cd0.w, cd1.x, cd1.y, cd1.z, cd1.w};
#pragma unroll
            for (int e = 0; e < 8; ++e) {
                float x = srcv + xs[e];
                float lr = fmaxf(x, 0.f) + ALPHA * fminf(x, 0.f);
                float pe = __expf(lr);
                unsigned long long mm = (e & 3) == 0 ? m0 : (e & 3) == 1 ? m1
                                      : (e & 3) == 2 ? m2 : m3;
                unsigned bit = (unsigned)(mm >> (hb + (e >> 2))) & 1u;
                p[e] = bit ? pe : 0.f;
            }
        }
        unsigned pw0, pw1, pw2, pw3;
        asm("v_cvt_pk_bf16_f32 %0, %1, %2" : "=v"(pw0) : "v"(p[0]), "v"(p[1]));
        asm("v_cvt_pk_bf16_f32 %0, %1, %2" : "=v"(pw1) : "v"(p[2]), "v"(p[3]));
        asm("v_cvt_pk_bf16_f32 %0, %1, %2" : "=v"(pw2) : "v"(p[4]), "v"(p[5]));
        asm("v_cvt_pk_bf16_f32 %0, %1, %2" : "=v"(pw3) : "v"(p[6]), "v"(p[7]));
        bf16x8 af = __builtin_bit_cast(bf16x8, make_uint4(pw0, pw1, pw2, pw3));

        acc0 = __builtin_amdgcn_mfma_f32_16x16x32_bf16(af, __builtin_bit_cast(bf16x8, cb0), acc0, 0, 0, 0);
        acc1 = __builtin_amdgcn_mfma_f32_16x16x32_bf16(af, __builtin_bit_cast(bf16x8, cb1), acc1, 0, 0, 0);
        acc2 = __builtin_amdgcn_mfma_f32_16x16x32_bf16(af, __builtin_bit_cast(bf16x8, cb2), acc2, 0, 0, 0);
        acc3 = __builtin_amdgcn_mfma_f32_16x16x32_bf16(af, __builtin_bit_cast(bf16x8, cb3), acc3, 0, 0, 0);
        accl = __builtin_amdgcn_mfma_f32_16x16x32_bf16(af, bones, accl, 0, 0, 0);

        cb0 = nb0; cb1 = nb1; cb2 = nb2; cb3 = nb3;
        cd0 = nd0; cd1 = nd1;
    }

    // accl: row m = g*4+reg, all 16 cols identical -> store from col lane r==0
    if (r == 0) {
        float* plo = pl + (size_t)task * 64 + w * 16 + g * 4;
        plo[0] = accl[0]; plo[1] = accl[1]; plo[2] = accl[2]; plo[3] = accl[3];
    }

    // C layout (verified): col = lane&15, row_m = (lane>>4)*4 + reg
    float* po = pacc + (size_t)task * 4096 + (size_t)(w * 16) * 64;
#pragma unroll
    for (int reg = 0; reg < 4; ++reg) {
        int m = g * 4 + reg;
        po[m * 64 + 0 * 16 + r] = acc0[reg];
        po[m * 64 + 1 * 16 + r] = acc1[reg];
        po[m * 64 + 2 * 16 + r] = acc2[reg];
        po[m * 64 + 3 * 16 + r] = acc3[reg];
    }
}

// K3: combine split partials + ELU. block=256 (4 waves), wave=row, lane=f.
__global__ __launch_bounds__(256) void gat_k3(const float* __restrict__ pl,
                                              const float* __restrict__ pacc,
                                              float* __restrict__ out) {
    int t = threadIdx.x;
    int wave = t >> 6, lane = t & 63;
    int row = blockIdx.x * 4 + wave;
    int rg = row >> 6, rr = row & 63;
    float L = 0.f, o = 0.f;
    for (int s2 = 0; s2 < NS; ++s2) {
        L += pl[(size_t)(rg * NS + s2) * 64 + rr];
        o += pacc[(size_t)(rg * NS + s2) * 4096 + rr * 64 + lane];
    }
    float hp = o / L;
    out[(size_t)row * 64 + lane] = hp > 0.f ? hp : __expf(hp) - 1.f;
}

extern "C" void kernel_launch(void* const* d_in, const int* in_sizes, int n_in,
                              void* d_out, int out_size, void* d_ws, size_t ws_size,
                              hipStream_t stream) {
    const float* h = (const float*)d_in[0];
    const int* adj = (const int*)d_in[1];
    const float* W = (const float*)d_in[2];
    const float* a = (const float*)d_in[3];
    float* out = (float*)d_out;
    float* ws = (float*)d_ws;

    // floats: Wh 524288 + src 8192 + dst 8192 + pl 16*8192 + pacc 16*524288
    //         + whbt2 262144 + adjb 2097152  ~= 46 MB  (ws is ~1 GiB)
    float* Wh = ws;
    float* src = Wh + (size_t)NN * FOUT;
    float* dst = src + NN;
    float* pl = dst + NN;
    float* pacc = pl + (size_t)128 * NS * 64;
    uint4* whbt2 = (uint4*)(pacc + (size_t)128 * NS * 4096);                  // 1 MB
    unsigned long long* adjb = (unsigned long long*)((float*)whbt2 + 262144); // 8 MB

    gat_k0<<<dim3(NN / 4), dim3(256), 0, stream>>>(adj, adjb);
    gat_k1<<<dim3(NN / 4), dim3(256), 0, stream>>>(h, W, a, Wh, src, dst);
    gat_k1b<<<dim3(NN / 32), dim3(256), 0, stream>>>(Wh, whbt2);
    gat_k2<<<dim3(NS, 128), dim3(256), 0, stream>>>(adjb, whbt2, src, dst, pl, pacc);
    gat_k3<<<dim3(NN / 4), dim3(256), 0, stream>>>(pl, pacc, out);
}